// Round 2
// baseline (173.328 us; speedup 1.0000x reference)
//
#include <hip/hip_runtime.h>
#include <hip/hip_bf16.h>

// MultiHeadRelationAwareAttention on MI355X (gfx950), bf16 MFMA pipeline:
//   conv_all : fp32 -> bf16 copies of x, Wq, Wk, Wv, Wo
//   gemm_qkv : Q=(x Wq^T+bq)*0.125*log2e -> [8][4096][64]; K likewise (scale 1);
//              V=(x Wv^T+bv) stored transposed per head -> [8][64][4096]
//   attn_fwd : flash attention in log2 domain; S^T = mfma(K,Q) so P^T C-frags
//              feed PV's B-operand directly (consistent-k-permutation trick)
//   gemm_out : out = attn Wo^T + bo (fp32)

typedef float    f32x4  __attribute__((ext_vector_type(4)));
typedef __bf16   bf16x8 __attribute__((ext_vector_type(8)));
typedef unsigned short u16;
typedef u16      u16x8  __attribute__((ext_vector_type(8)));
typedef u16      u16x4  __attribute__((ext_vector_type(4)));

__device__ __forceinline__ u16 f2bf(float f){
  __hip_bfloat16 h = __float2bfloat16(f);
  return __builtin_bit_cast(u16, h);
}
__device__ __forceinline__ float exp2_fast(float x){   // p = 2^x, scores pre-scaled by log2e
  float r; asm("v_exp_f32 %0, %1" : "=v"(r) : "v"(x)); return r;
}
__device__ __forceinline__ f32x4 mfma16(u16x8 a, u16x8 b, f32x4 c){
  return __builtin_amdgcn_mfma_f32_16x16x32_bf16(
      __builtin_bit_cast(bf16x8, a), __builtin_bit_cast(bf16x8, b), c, 0, 0, 0);
}
// XOR swizzle for 128B-row-stride LDS tiles. Involution on byte bits 4..6 keyed
// by bits 7..9: 16 lanes reading the same column-octet of 16 rows land on 8
// distinct 16B slots (2-way = free, m136). Applied on BOTH write & read sides.
__device__ __forceinline__ int swz7(int b){ return b ^ (((b >> 7) & 7) << 4); }

// ---------------------------------------------------------------- conv_all
__global__ __launch_bounds__(256) void conv_all(
    const float* __restrict__ x,
    const float* __restrict__ wq, const float* __restrict__ wk,
    const float* __restrict__ wv, const float* __restrict__ wo,
    u16* __restrict__ xb, u16* __restrict__ wqb, u16* __restrict__ wkb,
    u16* __restrict__ wvb, u16* __restrict__ wob)
{
  int i = blockIdx.x * 256 + threadIdx.x;   // float4 index, total 786432
  const float* s; u16* d; int j;
  if      (i < 524288) { s = x;  d = xb;  j = i; }
  else if (i < 589824) { s = wq; d = wqb; j = i - 524288; }
  else if (i < 655360) { s = wk; d = wkb; j = i - 589824; }
  else if (i < 720896) { s = wv; d = wvb; j = i - 655360; }
  else                 { s = wo; d = wob; j = i - 720896; }
  float4 v = ((const float4*)s)[j];
  u16x4 o; o[0] = f2bf(v.x); o[1] = f2bf(v.y); o[2] = f2bf(v.z); o[3] = f2bf(v.w);
  ((u16x4*)d)[j] = o;
}

// ------------------------------------------------------------- GEMM core
// C[64x128] tile of A[M][512] * W[512][512]^T.  4 waves (2x2), 16x16x32 MFMA,
// BK=64, double-buffered LDS, issue-early/write-late prefetch (T14),
// ONE barrier per kt-step.  As = 2*8KB, Bs = 2*16KB.
__device__ __forceinline__ void gemm_core_512(
    const u16* __restrict__ A, const u16* __restrict__ W,
    int bm, int bn, u16* As, u16* Bs, f32x4 (&acc)[2][4], int tid)
{
  const int lane = tid & 63, wid = tid >> 6;
  const int wm = wid >> 1, wn = wid & 1;
  const int c = lane & 15, g = lane >> 4;
  const int rr = tid >> 3, co = tid & 7;          // 32 rows per stage-iter
  const u16* Ab = A + (bm * 64 + rr) * 512 + co * 8;
  const u16* Wb = W + (bn * 128 + rr) * 512 + co * 8;
  // prologue: stage kt=0 into buffer 0
#pragma unroll
  for (int it = 0; it < 2; ++it)
    *(uint4*)((char*)As + swz7((it * 32 + rr) * 128 + co * 16)) =
        *(const uint4*)(Ab + it * 32 * 512);
#pragma unroll
  for (int it = 0; it < 4; ++it)
    *(uint4*)((char*)Bs + swz7((it * 32 + rr) * 128 + co * 16)) =
        *(const uint4*)(Wb + it * 32 * 512);
  __syncthreads();
  for (int kt = 0; kt < 8; ++kt) {
    const int cur = kt & 1;
    uint4 pa[2], pw[4];
    if (kt < 7) {                                  // issue next-tile loads early
#pragma unroll
      for (int it = 0; it < 2; ++it)
        pa[it] = *(const uint4*)(Ab + it * 32 * 512 + (kt + 1) * 64);
#pragma unroll
      for (int it = 0; it < 4; ++it)
        pw[it] = *(const uint4*)(Wb + it * 32 * 512 + (kt + 1) * 64);
    }
    const char* Ar = (const char*)As + cur * 8192;
    const char* Wr = (const char*)Bs + cur * 16384;
#pragma unroll
    for (int kk = 0; kk < 2; ++kk) {
      u16x8 af[2], bfr[4];
#pragma unroll
      for (int mf = 0; mf < 2; ++mf) {
        int row = wm * 32 + mf * 16 + c;
        af[mf] = *(const u16x8*)(Ar + swz7(row * 128 + kk * 64 + g * 16));
      }
#pragma unroll
      for (int nf = 0; nf < 4; ++nf) {
        int row = wn * 64 + nf * 16 + c;
        bfr[nf] = *(const u16x8*)(Wr + swz7(row * 128 + kk * 64 + g * 16));
      }
#pragma unroll
      for (int mf = 0; mf < 2; ++mf)
#pragma unroll
        for (int nf = 0; nf < 4; ++nf)
          acc[mf][nf] = mfma16(af[mf], bfr[nf], acc[mf][nf]);
    }
    if (kt < 7) {                                  // write-late into other buffer
      char* Ad = (char*)As + (cur ^ 1) * 8192;
      char* Wd = (char*)Bs + (cur ^ 1) * 16384;
#pragma unroll
      for (int it = 0; it < 2; ++it)
        *(uint4*)(Ad + swz7((it * 32 + rr) * 128 + co * 16)) = pa[it];
#pragma unroll
      for (int it = 0; it < 4; ++it)
        *(uint4*)(Wd + swz7((it * 32 + rr) * 128 + co * 16)) = pw[it];
    }
    __syncthreads();                               // one barrier per kt (dbuf-safe)
  }
}

// ------------------------------------------------------------- gemm_qkv
__global__ __launch_bounds__(256) void gemm_qkv(
    const u16* __restrict__ xb,
    const u16* __restrict__ wqb, const u16* __restrict__ wkb, const u16* __restrict__ wvb,
    const float* __restrict__ bq, const float* __restrict__ bk, const float* __restrict__ bv,
    u16* __restrict__ Qw, u16* __restrict__ Kw, u16* __restrict__ Vt)
{
  __shared__ __align__(16) u16 As[2 * 64 * 64];
  __shared__ __align__(16) u16 Bs[2 * 128 * 64];
  const int tid = threadIdx.x, z = blockIdx.z;
  const int bm = blockIdx.x, bn = blockIdx.y;
  const u16*   W    = (z == 0) ? wqb : (z == 1) ? wkb : wvb;
  const float* bias = (z == 0) ? bq : (z == 1) ? bk : bv;
  const f32x4 Z4 = {0.f, 0.f, 0.f, 0.f};
  f32x4 acc[2][4];
#pragma unroll
  for (int a = 0; a < 2; ++a)
#pragma unroll
    for (int b = 0; b < 4; ++b) acc[a][b] = Z4;
  gemm_core_512(xb, W, bm, bn, As, Bs, acc, tid);
  const int lane = tid & 63, wid = tid >> 6;
  const int wm = wid >> 1, wn = wid & 1, c = lane & 15, g = lane >> 4;
  // Q: fold 1/sqrt(dk) AND log2(e) (softmax runs in exp2 domain)
  const float sc = (z == 0) ? 0.125f * 1.44269504088896f : 1.0f;
#pragma unroll
  for (int mf = 0; mf < 2; ++mf)
#pragma unroll
    for (int nf = 0; nf < 4; ++nf) {
      int o  = bn * 128 + wn * 64 + nf * 16 + c;
      int h  = o >> 6, d = o & 63;
      int ib = bm * 64 + wm * 32 + mf * 16 + 4 * g;  // 4 consecutive rows
      float bb = bias[o];
      f32x4 v = acc[mf][nf];
      if (z == 2) {           // V -> transposed per head [8][64][4096]
        u16x4 pk;
#pragma unroll
        for (int r = 0; r < 4; ++r) pk[r] = f2bf(v[r] + bb);
        *(u16x4*)&Vt[h * 262144 + d * 4096 + ib] = pk;
      } else {                // Q/K -> head-major [8][4096][64]
        u16* out = (z == 0) ? Qw : Kw;
#pragma unroll
        for (int r = 0; r < 4; ++r)
          out[h * 262144 + (ib + r) * 64 + d] = f2bf((v[r] + bb) * sc);
      }
    }
}

// ------------------------------------------------------------- attn_fwd
// Grid 256: blockIdx.x&7 = head (-> XCD-local K/V in L2), >>3 = q-block.
// 256 threads = 4 waves, each wave owns 32 q (2 n-frags); BQ=128, BKV=64,
// double-buffered K/V LDS, one barrier per tile, issue-early/write-late stage.
// Softmax in log2 domain (Q pre-scaled by 0.125*log2e), defer-rescale THR=8.
__global__ __launch_bounds__(256) void attn_fwd(
    const u16* __restrict__ Qw, const u16* __restrict__ Kw, const u16* __restrict__ Vt,
    u16* __restrict__ ab)
{
  __shared__ __align__(16) u16 Qs[128 * 64];      // 16KB
  __shared__ __align__(16) u16 Ks[2 * 64 * 64];   // 16KB dbuf
  __shared__ __align__(16) u16 Vs[2 * 64 * 64];   // 16KB dbuf (V^T tiles)
  const int tid = threadIdx.x, lane = tid & 63, w = tid >> 6;
  const int c = lane & 15, g = lane >> 4;
  const int h = blockIdx.x & 7, qb = blockIdx.x >> 3, q0 = qb * 128;
  const u16* gQ = Qw + h * 262144;
  const u16* gK = Kw + h * 262144;
  const u16* gV = Vt + h * 262144;

  // stage Q [128][64] (already scaled)
#pragma unroll
  for (int it = 0; it < 4; ++it) {
    int beta = it * 256 + tid, r = beta >> 3, co = beta & 7;
    uint4 v = *(const uint4*)(gQ + (q0 + r) * 64 + co * 8);
    *(uint4*)((char*)Qs + swz7(r * 128 + co * 16)) = v;
  }
  // stage K,V tile 0 into buffer 0 (K tile [64 kv][64 d], V^T tile [64 d][64 kv])
#pragma unroll
  for (int it = 0; it < 2; ++it) {
    int beta = it * 256 + tid, r = beta >> 3, co = beta & 7;
    uint4 vk = *(const uint4*)(gK + r * 64 + co * 8);
    uint4 vv = *(const uint4*)(gV + r * 4096 + co * 8);
    int by = swz7(r * 128 + co * 16);
    *(uint4*)((char*)Ks + by) = vk;
    *(uint4*)((char*)Vs + by) = vv;
  }
  __syncthreads();

  // hoist Q B-frags (per wave: q = w*32 + nf*16 + c)
  u16x8 qf[2][2];
#pragma unroll
  for (int nf = 0; nf < 2; ++nf)
#pragma unroll
    for (int kk = 0; kk < 2; ++kk) {
      int q = w * 32 + nf * 16 + c;
      qf[nf][kk] = *(const u16x8*)((const char*)Qs + swz7(q * 128 + kk * 64 + g * 16));
    }

  const f32x4 Z4 = {0.f, 0.f, 0.f, 0.f};
  f32x4 o_[4][2];                      // O^T: rows d (4 frags), cols q (2 nf)
#pragma unroll
  for (int mfd = 0; mfd < 4; ++mfd) { o_[mfd][0] = Z4; o_[mfd][1] = Z4; }
  float m_run[2] = {-1e30f, -1e30f};
  float l_run[2] = {0.f, 0.f};

  for (int t = 0; t < 64; ++t) {
    const int cur = t & 1;
    const char* kb = (const char*)Ks + cur * 8192;
    const char* vb = (const char*)Vs + cur * 8192;
    uint4 rgK[2], rgV[2];
    if (t < 63) {                      // issue next-tile loads early (T14)
      const int kv1 = (t + 1) * 64;
#pragma unroll
      for (int it = 0; it < 2; ++it) {
        int beta = it * 256 + tid, r = beta >> 3, co = beta & 7;
        rgK[it] = *(const uint4*)(gK + (kv1 + r) * 64 + co * 8);
        rgV[it] = *(const uint4*)(gV + r * 4096 + kv1 + co * 8);
      }
    }

    // S^T = mfma(K, Q): C rows = kv (16mf + 4g + r), cols = q (c)
    f32x4 s[4][2];
#pragma unroll
    for (int mf = 0; mf < 4; ++mf) { s[mf][0] = Z4; s[mf][1] = Z4; }
#pragma unroll
    for (int kk = 0; kk < 2; ++kk)
#pragma unroll
      for (int mf = 0; mf < 4; ++mf) {
        u16x8 kf = *(const u16x8*)(kb + swz7((c + 16 * mf) * 128 + kk * 64 + g * 16));
        s[mf][0] = mfma16(kf, qf[0][kk], s[mf][0]);
        s[mf][1] = mfma16(kf, qf[1][kk], s[mf][1]);
      }

    // online softmax per q column, log2 domain (stats replicated across g-groups)
#pragma unroll
    for (int nf = 0; nf < 2; ++nf) {
      float mt = s[0][nf][0];
#pragma unroll
      for (int mf = 0; mf < 4; ++mf)
#pragma unroll
        for (int r = 0; r < 4; ++r) mt = fmaxf(mt, s[mf][nf][r]);
      mt = fmaxf(mt, __shfl_xor(mt, 16));
      mt = fmaxf(mt, __shfl_xor(mt, 32));
      if (!__all(mt - m_run[nf] <= 8.0f)) {   // T13: defer-rescale, THR=8 (2^8 bound)
        float mn = fmaxf(m_run[nf], mt);
        float al = exp2_fast(m_run[nf] - mn);
        m_run[nf] = mn;
        l_run[nf] *= al;
#pragma unroll
        for (int mfd = 0; mfd < 4; ++mfd) o_[mfd][nf] *= al;
      }
      float mn = m_run[nf], lt = 0.f;
#pragma unroll
      for (int mf = 0; mf < 4; ++mf)
#pragma unroll
        for (int r = 0; r < 4; ++r) {
          float p = exp2_fast(s[mf][nf][r] - mn);
          s[mf][nf][r] = p;
          lt += p;
        }
      lt += __shfl_xor(lt, 16);
      lt += __shfl_xor(lt, 32);
      l_run[nf] += lt;
    }

    // PV: O^T += V^T * P^T.  P^T B-frag slot k-map {4g+j | 16+4g+(j-4)} equals
    // the C-frag row mapping (lane-local); V^T A-frags read with the SAME
    // slot k-map (two b64s at +0/+32B) -> consistent contraction, correct.
#pragma unroll
    for (int kap = 0; kap < 2; ++kap) {
      u16x8 pb[2];
#pragma unroll
      for (int nf = 0; nf < 2; ++nf) {
        u16x8 t8;
#pragma unroll
        for (int j = 0; j < 4; ++j) {
          t8[j]     = f2bf(s[2 * kap][nf][j]);
          t8[4 + j] = f2bf(s[2 * kap + 1][nf][j]);
        }
        pb[nf] = t8;
      }
#pragma unroll
      for (int mfd = 0; mfd < 4; ++mfd) {
        int e = (c + 16 * mfd) * 128 + kap * 64 + g * 8;   // bytes in V^T tile
        u16x4 lo = *(const u16x4*)(vb + swz7(e));
        u16x4 hi = *(const u16x4*)(vb + swz7(e + 32));
        u16x8 vf = __builtin_shufflevector(lo, hi, 0, 1, 2, 3, 4, 5, 6, 7);
        o_[mfd][0] = mfma16(vf, pb[0], o_[mfd][0]);
        o_[mfd][1] = mfma16(vf, pb[1], o_[mfd][1]);
      }
    }

    if (t < 63) {                      // write-late into the other buffer
      char* kd = (char*)Ks + (cur ^ 1) * 8192;
      char* vd = (char*)Vs + (cur ^ 1) * 8192;
#pragma unroll
      for (int it = 0; it < 2; ++it) {
        int beta = it * 256 + tid, r = beta >> 3, co = beta & 7;
        int by = swz7(r * 128 + co * 16);
        *(uint4*)(kd + by) = rgK[it];
        *(uint4*)(vd + by) = rgV[it];
      }
    }
    __syncthreads();                   // one barrier per tile (dbuf-safe)
  }

  // epilogue: attn[q][h*64+d] = O^T[d][q] / l   (packed u16x4 stores)
#pragma unroll
  for (int nf = 0; nf < 2; ++nf) {
    float inv = 1.0f / l_run[nf];
    int q = q0 + w * 32 + nf * 16 + c;
#pragma unroll
    for (int mfd = 0; mfd < 4; ++mfd) {
      u16x4 pk;
#pragma unroll
      for (int r = 0; r < 4; ++r) pk[r] = f2bf(o_[mfd][nf][r] * inv);
      *(u16x4*)&ab[q * 512 + h * 64 + mfd * 16 + 4 * g] = pk;
    }
  }
}

// ------------------------------------------------------------- gemm_out
__global__ __launch_bounds__(256) void gemm_out(
    const u16* __restrict__ ab, const u16* __restrict__ wob,
    const float* __restrict__ bo, float* __restrict__ out)
{
  __shared__ __align__(16) u16 As[2 * 64 * 64];
  __shared__ __align__(16) u16 Bs[2 * 128 * 64];
  const int tid = threadIdx.x, bm = blockIdx.x, bn = blockIdx.y;
  const f32x4 Z4 = {0.f, 0.f, 0.f, 0.f};
  f32x4 acc[2][4];
#pragma unroll
  for (int a = 0; a < 2; ++a)
#pragma unroll
    for (int b = 0; b < 4; ++b) acc[a][b] = Z4;
  gemm_core_512(ab, wob, bm, bn, As, Bs, acc, tid);
  const int lane = tid & 63, wid = tid >> 6;
  const int wm = wid >> 1, wn = wid & 1, c = lane & 15, g = lane >> 4;
#pragma unroll
  for (int mf = 0; mf < 2; ++mf)
#pragma unroll
    for (int nf = 0; nf < 4; ++nf) {
      int o  = bn * 128 + wn * 64 + nf * 16 + c;
      int ib = bm * 64 + wm * 32 + mf * 16 + 4 * g;
      float bb = bo[o];
      f32x4 v = acc[mf][nf];
#pragma unroll
      for (int r = 0; r < 4; ++r) out[(ib + r) * 512 + o] = v[r] + bb;
    }
}

// ------------------------------------------------------------- launch
extern "C" void kernel_launch(void* const* d_in, const int* in_sizes, int n_in,
                              void* d_out, int out_size, void* d_ws, size_t ws_size,
                              hipStream_t stream) {
  (void)in_sizes; (void)n_in; (void)out_size; (void)ws_size;
  const float* x  = (const float*)d_in[0];
  const float* Wq = (const float*)d_in[1];
  const float* bq = (const float*)d_in[2];
  const float* Wk = (const float*)d_in[3];
  const float* bk = (const float*)d_in[4];
  const float* Wv = (const float*)d_in[5];
  const float* bv = (const float*)d_in[6];
  const float* Wo = (const float*)d_in[7];
  const float* bo = (const float*)d_in[8];
  char* ws = (char*)d_ws;
  u16* xb  = (u16*)(ws + 0);          // x bf16           4 MB
  u16* wqb = (u16*)(ws + 4194304);    // Wq bf16        0.5 MB
  u16* wkb = (u16*)(ws + 4718592);
  u16* wvb = (u16*)(ws + 5242880);
  u16* wob = (u16*)(ws + 5767168);
  u16* Qw  = (u16*)(ws + 6291456);    // Q  [8][4096][64] 4 MB (scaled 0.125*log2e)
  u16* Kw  = (u16*)(ws + 10485760);   // K  [8][4096][64] 4 MB
  u16* Vt  = (u16*)(ws + 14680064);   // V^T [8][64][4096] 4 MB
  u16* ab  = (u16*)(ws + 18874368);   // attn bf16 [4096][512] 4 MB

  conv_all<<<3072, 256, 0, stream>>>(x, Wq, Wk, Wv, Wo, xb, wqb, wkb, wvb, wob);
  gemm_qkv<<<dim3(64, 4, 3), 256, 0, stream>>>(xb, wqb, wkb, wvb, bq, bk, bv, Qw, Kw, Vt);
  attn_fwd<<<256, 256, 0, stream>>>(Qw, Kw, Vt, ab);
  gemm_out<<<dim3(64, 4), 256, 0, stream>>>(ab, wob, bo, (float*)d_out);
}